// Round 1
// baseline (1313.662 us; speedup 1.0000x reference)
//
#include <hip/hip_runtime.h>

static constexpr int HIDDEN = 128;

// One edge handled by 32 consecutive lanes; each lane moves one float4 chunk.
__global__ void __launch_bounds__(256) scatter_kernel(
    const float* __restrict__ h,
    const int* __restrict__ src,
    const int* __restrict__ dst,
    float* __restrict__ agg,     // = d_out, pre-zeroed
    int* __restrict__ indeg,     // pre-zeroed
    int n_edges) {
  int gid = blockIdx.x * 256 + threadIdx.x;
  int e = gid >> 5;
  if (e >= n_edges) return;
  int c = gid & 31;
  int s = src[e];
  int d = dst[e];
  float4 v = reinterpret_cast<const float4*>(h + (size_t)s * HIDDEN)[c];
  float* p = agg + (size_t)d * HIDDEN + c * 4;
  atomicAdd(p + 0, v.x);
  atomicAdd(p + 1, v.y);
  atomicAdd(p + 2, v.z);
  atomicAdd(p + 3, v.w);
  if (c == 0) atomicAdd(indeg + d, 1);
}

// out[i] = indeg[i]>0 ? agg[i] @ W.T + b : h[i].   In-place: agg == out.
// 32 lanes per node (2 nodes per wave, 8 per block). W transposed into LDS.
__global__ void __launch_bounds__(256, 2) update_kernel(
    const float* __restrict__ agg,
    const float* __restrict__ h,
    const float* __restrict__ W,   // [j][k] row-major
    const float* __restrict__ b,
    const int* __restrict__ indeg,
    float* __restrict__ out,
    int n_nodes) {
  __shared__ float Wt[HIDDEN][HIDDEN];  // Wt[k][j] = W[j][k]
  for (int i = threadIdx.x; i < HIDDEN * HIDDEN / 4; i += 256) {
    int idx = i * 4;
    int j = idx >> 7;        // W row
    int k = idx & 127;       // W col base
    float4 w = *reinterpret_cast<const float4*>(W + j * HIDDEN + k);
    Wt[k + 0][j] = w.x;
    Wt[k + 1][j] = w.y;
    Wt[k + 2][j] = w.z;
    Wt[k + 3][j] = w.w;
  }
  __syncthreads();

  const int lane = threadIdx.x & 31;   // float4 chunk / j-chunk owner
  const int group = threadIdx.x >> 5;  // node within batch of 8
  const int j0 = lane * 4;
  const float4 bias = *reinterpret_cast<const float4*>(b + j0);

  const int nb = (n_nodes + 7) >> 3;
  for (int batch = blockIdx.x; batch < nb; batch += gridDim.x) {
    int node = batch * 8 + group;
    if (node >= n_nodes) continue;
    // Preload entire agg row into the group's registers (read-before-write
    // makes the in-place overwrite safe: lockstep wave, loads precede stores).
    const float4 a0 =
        reinterpret_cast<const float4*>(agg + (size_t)node * HIDDEN)[lane];
    const float* av = reinterpret_cast<const float*>(&a0);
    float4 acc = bias;
#pragma unroll
    for (int k = 0; k < HIDDEN; ++k) {
      float aval = __shfl(av[k & 3], k >> 2, 32);  // agg[node][k] broadcast
      float4 w = *reinterpret_cast<const float4*>(&Wt[k][j0]);
      acc.x = fmaf(aval, w.x, acc.x);
      acc.y = fmaf(aval, w.y, acc.y);
      acc.z = fmaf(aval, w.z, acc.z);
      acc.w = fmaf(aval, w.w, acc.w);
    }
    float4 res;
    if (indeg[node] > 0) {
      res = acc;
    } else {
      res = reinterpret_cast<const float4*>(h + (size_t)node * HIDDEN)[lane];
    }
    reinterpret_cast<float4*>(out + (size_t)node * HIDDEN)[lane] = res;
  }
}

extern "C" void kernel_launch(void* const* d_in, const int* in_sizes, int n_in,
                              void* d_out, int out_size, void* d_ws, size_t ws_size,
                              hipStream_t stream) {
  const float* h = (const float*)d_in[0];
  const float* W = (const float*)d_in[1];
  const float* b = (const float*)d_in[2];
  const int* src = (const int*)d_in[3];
  const int* dst = (const int*)d_in[4];
  float* out = (float*)d_out;
  const int n_nodes = in_sizes[0] / HIDDEN;
  const int n_edges = in_sizes[3];
  int* indeg = (int*)d_ws;

  // agg lives in d_out; harness re-poisons both every timed call -> zero here.
  hipMemsetAsync(d_out, 0, (size_t)out_size * sizeof(float), stream);
  hipMemsetAsync(d_ws, 0, (size_t)n_nodes * sizeof(int), stream);

  const int sblocks = (n_edges * 32 + 255) / 256;
  scatter_kernel<<<sblocks, 256, 0, stream>>>(h, src, dst, out, indeg, n_edges);
  update_kernel<<<512, 256, 0, stream>>>(out, h, W, b, indeg, out, n_nodes);
}

// Round 2
// 321.165 us; speedup vs baseline: 4.0903x; 4.0903x over previous
//
#include <hip/hip_runtime.h>

static constexpr int HIDDEN = 128;

// ---------------------------------------------------------------------------
// CSR-build path (primary): hist -> scan -> fill -> fused gather+GEMV.
// ---------------------------------------------------------------------------

__global__ void __launch_bounds__(256) hist_kernel(
    const int* __restrict__ dst, int* __restrict__ counts, int n_edges) {
  int i = blockIdx.x * 256 + threadIdx.x;
  if (i < n_edges) atomicAdd(&counts[dst[i]], 1);
}

// Single-block hierarchical exclusive scan: offsets[i] = sum(counts[0..i-1]).
__global__ void __launch_bounds__(1024) scan_kernel(
    const int* __restrict__ counts, int* __restrict__ offsets, int n) {
  __shared__ int part[1024];
  const int t = threadIdx.x;
  const int C = (n + 1023) / 1024;
  const int base = t * C;
  int sum = 0;
  for (int j = 0; j < C; ++j) {
    int idx = base + j;
    if (idx < n) sum += counts[idx];
  }
  part[t] = sum;
  __syncthreads();
  for (int s = 1; s < 1024; s <<= 1) {
    int v = (t >= s) ? part[t - s] : 0;
    __syncthreads();
    part[t] += v;
    __syncthreads();
  }
  int run = part[t] - sum;  // exclusive prefix for this chunk
  for (int j = 0; j < C; ++j) {
    int idx = base + j;
    if (idx < n) {
      offsets[idx] = run;
      run += counts[idx];
    }
  }
}

// offsets doubles as the fill cursor; after this kernel offsets[d] == end_d.
__global__ void __launch_bounds__(256) fill_kernel(
    const int* __restrict__ src, const int* __restrict__ dst,
    int* __restrict__ offsets, int* __restrict__ esorted, int n_edges) {
  int i = blockIdx.x * 256 + threadIdx.x;
  if (i < n_edges) {
    int pos = atomicAdd(&offsets[dst[i]], 1);
    esorted[pos] = src[i];
  }
}

// Per node: 32 lanes, lane owns float4 chunk. Register-accumulate h[src] over
// the node's CSR segment, then GEMV vs LDS-transposed W, write out once.
__global__ void __launch_bounds__(256, 2) gather_update_kernel(
    const float* __restrict__ h,
    const float* __restrict__ W,   // [j][k] row-major
    const float* __restrict__ b,
    const int* __restrict__ counts,   // indeg
    const int* __restrict__ ends,     // mutated offsets: ends[d] = end of seg d
    const int* __restrict__ esorted,  // src ids sorted by dst
    float* __restrict__ out,
    int n_nodes) {
  __shared__ float Wt[HIDDEN][HIDDEN];  // Wt[k][j] = W[j][k]
  for (int i = threadIdx.x; i < HIDDEN * HIDDEN / 4; i += 256) {
    int idx = i * 4;
    int j = idx >> 7;
    int k = idx & 127;
    float4 w = *reinterpret_cast<const float4*>(W + j * HIDDEN + k);
    Wt[k + 0][j] = w.x;
    Wt[k + 1][j] = w.y;
    Wt[k + 2][j] = w.z;
    Wt[k + 3][j] = w.w;
  }
  __syncthreads();

  const int lane = threadIdx.x & 31;
  const int group = threadIdx.x >> 5;
  const int j0 = lane * 4;
  const float4 bias = *reinterpret_cast<const float4*>(b + j0);

  const int nb = (n_nodes + 7) >> 3;
  for (int batch = blockIdx.x; batch < nb; batch += gridDim.x) {
    int node = batch * 8 + group;
    if (node >= n_nodes) continue;
    const int deg = counts[node];
    float4 res;
    if (deg == 0) {
      res = reinterpret_cast<const float4*>(h + (size_t)node * HIDDEN)[lane];
    } else {
      const int start = ends[node] - deg;
      float4 acc = {0.f, 0.f, 0.f, 0.f};
      for (int basei = 0; basei < deg; basei += 32) {
        int sreg = 0;
        if (basei + lane < deg) sreg = esorted[start + basei + lane];
        const int m = min(32, deg - basei);
        for (int jj = 0; jj < m; ++jj) {
          int s = __shfl(sreg, jj, 32);
          float4 v = reinterpret_cast<const float4*>(h + (size_t)s * HIDDEN)[lane];
          acc.x += v.x;
          acc.y += v.y;
          acc.z += v.z;
          acc.w += v.w;
        }
      }
      // GEMV: out_chunk[j0..j0+3] = sum_k agg[k] * Wt[k][j0..j0+3] + bias
      const float* av = reinterpret_cast<const float*>(&acc);
      float4 o = bias;
#pragma unroll
      for (int k = 0; k < HIDDEN; ++k) {
        float aval = __shfl(av[k & 3], k >> 2, 32);
        float4 w = *reinterpret_cast<const float4*>(&Wt[k][j0]);
        o.x = fmaf(aval, w.x, o.x);
        o.y = fmaf(aval, w.y, o.y);
        o.z = fmaf(aval, w.z, o.z);
        o.w = fmaf(aval, w.w, o.w);
      }
      res = o;
    }
    reinterpret_cast<float4*>(out + (size_t)node * HIDDEN)[lane] = res;
  }
}

// ---------------------------------------------------------------------------
// Fallback path (ws too small): R0 atomic scatter + update. Kept for safety.
// ---------------------------------------------------------------------------

__global__ void __launch_bounds__(256) scatter_kernel(
    const float* __restrict__ h, const int* __restrict__ src,
    const int* __restrict__ dst, float* __restrict__ agg,
    int* __restrict__ indeg, int n_edges) {
  int gid = blockIdx.x * 256 + threadIdx.x;
  int e = gid >> 5;
  if (e >= n_edges) return;
  int c = gid & 31;
  int s = src[e];
  int d = dst[e];
  float4 v = reinterpret_cast<const float4*>(h + (size_t)s * HIDDEN)[c];
  float* p = agg + (size_t)d * HIDDEN + c * 4;
  atomicAdd(p + 0, v.x);
  atomicAdd(p + 1, v.y);
  atomicAdd(p + 2, v.z);
  atomicAdd(p + 3, v.w);
  if (c == 0) atomicAdd(indeg + d, 1);
}

__global__ void __launch_bounds__(256, 2) update_kernel(
    const float* __restrict__ agg, const float* __restrict__ h,
    const float* __restrict__ W, const float* __restrict__ b,
    const int* __restrict__ indeg, float* __restrict__ out, int n_nodes) {
  __shared__ float Wt[HIDDEN][HIDDEN];
  for (int i = threadIdx.x; i < HIDDEN * HIDDEN / 4; i += 256) {
    int idx = i * 4;
    int j = idx >> 7;
    int k = idx & 127;
    float4 w = *reinterpret_cast<const float4*>(W + j * HIDDEN + k);
    Wt[k + 0][j] = w.x;
    Wt[k + 1][j] = w.y;
    Wt[k + 2][j] = w.z;
    Wt[k + 3][j] = w.w;
  }
  __syncthreads();
  const int lane = threadIdx.x & 31;
  const int group = threadIdx.x >> 5;
  const int j0 = lane * 4;
  const float4 bias = *reinterpret_cast<const float4*>(b + j0);
  const int nb = (n_nodes + 7) >> 3;
  for (int batch = blockIdx.x; batch < nb; batch += gridDim.x) {
    int node = batch * 8 + group;
    if (node >= n_nodes) continue;
    const float4 a0 =
        reinterpret_cast<const float4*>(agg + (size_t)node * HIDDEN)[lane];
    const float* av = reinterpret_cast<const float*>(&a0);
    float4 acc = bias;
#pragma unroll
    for (int k = 0; k < HIDDEN; ++k) {
      float aval = __shfl(av[k & 3], k >> 2, 32);
      float4 w = *reinterpret_cast<const float4*>(&Wt[k][j0]);
      acc.x = fmaf(aval, w.x, acc.x);
      acc.y = fmaf(aval, w.y, acc.y);
      acc.z = fmaf(aval, w.z, acc.z);
      acc.w = fmaf(aval, w.w, acc.w);
    }
    float4 res;
    if (indeg[node] > 0) {
      res = acc;
    } else {
      res = reinterpret_cast<const float4*>(h + (size_t)node * HIDDEN)[lane];
    }
    reinterpret_cast<float4*>(out + (size_t)node * HIDDEN)[lane] = res;
  }
}

// ---------------------------------------------------------------------------

extern "C" void kernel_launch(void* const* d_in, const int* in_sizes, int n_in,
                              void* d_out, int out_size, void* d_ws, size_t ws_size,
                              hipStream_t stream) {
  const float* h = (const float*)d_in[0];
  const float* W = (const float*)d_in[1];
  const float* b = (const float*)d_in[2];
  const int* src = (const int*)d_in[3];
  const int* dst = (const int*)d_in[4];
  float* out = (float*)d_out;
  const int n_nodes = in_sizes[0] / HIDDEN;
  const int n_edges = in_sizes[3];

  const int n_round = (n_nodes + 63) & ~63;
  const size_t need = ((size_t)2 * n_round + n_edges) * sizeof(int);

  if (ws_size >= need) {
    int* counts = (int*)d_ws;            // [n_round]
    int* offsets = counts + n_round;     // [n_round], becomes ends[] after fill
    int* esorted = offsets + n_round;    // [n_edges]

    hipMemsetAsync(counts, 0, (size_t)n_nodes * sizeof(int), stream);

    const int eblocks = (n_edges + 255) / 256;
    hist_kernel<<<eblocks, 256, 0, stream>>>(dst, counts, n_edges);
    scan_kernel<<<1, 1024, 0, stream>>>(counts, offsets, n_nodes);
    fill_kernel<<<eblocks, 256, 0, stream>>>(src, dst, offsets, esorted, n_edges);
    gather_update_kernel<<<512, 256, 0, stream>>>(h, W, b, counts, offsets,
                                                  esorted, out, n_nodes);
  } else {
    // Fallback: atomic scatter into d_out (agg), indeg in ws.
    int* indeg = (int*)d_ws;
    hipMemsetAsync(d_out, 0, (size_t)out_size * sizeof(float), stream);
    hipMemsetAsync(d_ws, 0, (size_t)n_nodes * sizeof(int), stream);
    const int sblocks = (n_edges * 32 + 255) / 256;
    scatter_kernel<<<sblocks, 256, 0, stream>>>(h, src, dst, out, indeg, n_edges);
    update_kernel<<<512, 256, 0, stream>>>(out, h, W, b, indeg, out, n_nodes);
  }
}

// Round 4
// 232.848 us; speedup vs baseline: 5.6417x; 1.3793x over previous
//
#include <hip/hip_runtime.h>
#include <hip/hip_bf16.h>

static constexpr int HIDDEN = 128;

__device__ inline ushort f2bf(float x) {
  __hip_bfloat16 t = __float2bfloat16(x);
  return *reinterpret_cast<ushort*>(&t);
}

// ---------------------------------------------------------------------------
// CSR build: hist -> 3-phase parallel scan -> fill
// ---------------------------------------------------------------------------

__global__ void __launch_bounds__(256) hist_kernel(
    const int* __restrict__ dst, int* __restrict__ counts, int n_edges) {
  int i = blockIdx.x * 256 + threadIdx.x;
  if (i < n_edges) atomicAdd(&counts[dst[i]], 1);
}

// Phase A: per-tile (1024 elements) sums.
__global__ void __launch_bounds__(256) scanA_kernel(
    const int* __restrict__ counts, int* __restrict__ tilesums, int n) {
  const int t = threadIdx.x;
  const int base = blockIdx.x * 1024 + t * 4;
  int s = 0;
  if (base + 3 < n) {
    int4 v = *reinterpret_cast<const int4*>(counts + base);
    s = v.x + v.y + v.z + v.w;
  } else {
    for (int j = 0; j < 4; ++j)
      if (base + j < n) s += counts[base + j];
  }
  for (int off = 1; off < 64; off <<= 1) s += __shfl_xor(s, off, 64);
  __shared__ int wp[4];
  if ((t & 63) == 0) wp[t >> 6] = s;
  __syncthreads();
  if (t == 0) tilesums[blockIdx.x] = wp[0] + wp[1] + wp[2] + wp[3];
}

// Phase B: exclusive scan of <=64 tile sums, one wave.
__global__ void __launch_bounds__(64) scanB_kernel(int* tilesums, int nt) {
  int t = threadIdx.x;
  int v = (t < nt) ? tilesums[t] : 0;
  int orig = v;
  for (int off = 1; off < 64; off <<= 1) {
    int u = __shfl_up(v, off, 64);
    if (t >= off) v += u;
  }
  if (t < nt) tilesums[t] = v - orig;
}

// Phase C: write exclusive offsets.
__global__ void __launch_bounds__(256) scanC_kernel(
    const int* __restrict__ counts, const int* __restrict__ tileprefix,
    int* __restrict__ offsets, int n) {
  const int t = threadIdx.x;
  const int base = blockIdx.x * 1024 + t * 4;
  int4 v = {0, 0, 0, 0};
  const bool full = (base + 3 < n);
  if (full) {
    v = *reinterpret_cast<const int4*>(counts + base);
  } else {
    if (base + 0 < n) v.x = counts[base + 0];
    if (base + 1 < n) v.y = counts[base + 1];
    if (base + 2 < n) v.z = counts[base + 2];
    if (base + 3 < n) v.w = counts[base + 3];
  }
  const int s = v.x + v.y + v.z + v.w;
  int inc = s;
  for (int off = 1; off < 64; off <<= 1) {
    int u = __shfl_up(inc, off, 64);
    if ((t & 63) >= off) inc += u;
  }
  const int excl = inc - s;
  __shared__ int wp[4];
  if ((t & 63) == 63) wp[t >> 6] = inc;
  __syncthreads();
  int wbase = 0;
  for (int w = 0; w < (t >> 6); ++w) wbase += wp[w];
  int p = tileprefix[blockIdx.x] + wbase + excl;
  if (full) {
    int4 o;
    o.x = p;
    o.y = p + v.x;
    o.z = p + v.x + v.y;
    o.w = p + v.x + v.y + v.z;
    *reinterpret_cast<int4*>(offsets + base) = o;
  } else {
    int run = p;
    if (base + 0 < n) { offsets[base + 0] = run; run += v.x; }
    if (base + 1 < n) { offsets[base + 1] = run; run += v.y; }
    if (base + 2 < n) { offsets[base + 2] = run; run += v.z; }
    if (base + 3 < n) { offsets[base + 3] = run; }
  }
}

// offsets doubles as the fill cursor; afterwards offsets[d] == end_d.
__global__ void __launch_bounds__(256) fill_kernel(
    const int* __restrict__ src, const int* __restrict__ dst,
    int* __restrict__ offsets, int* __restrict__ esorted, int n_edges) {
  int i = blockIdx.x * 256 + threadIdx.x;
  if (i < n_edges) {
    int pos = atomicAdd(&offsets[dst[i]], 1);
    esorted[pos] = src[i];
  }
}

// ---------------------------------------------------------------------------
// hW = h @ W.T  (bf16 out; bias NOT added here). 32 lanes/node, Wt in LDS.
// ---------------------------------------------------------------------------
__global__ void __launch_bounds__(256, 2) transform_kernel(
    const float* __restrict__ h, const float* __restrict__ W,
    ushort* __restrict__ hW, int n_nodes) {
  __shared__ float Wt[HIDDEN][HIDDEN];  // Wt[k][j] = W[j][k]
  for (int i = threadIdx.x; i < HIDDEN * HIDDEN / 4; i += 256) {
    int idx = i * 4;
    int j = idx >> 7;
    int k = idx & 127;
    float4 w = *reinterpret_cast<const float4*>(W + j * HIDDEN + k);
    Wt[k + 0][j] = w.x;
    Wt[k + 1][j] = w.y;
    Wt[k + 2][j] = w.z;
    Wt[k + 3][j] = w.w;
  }
  __syncthreads();

  const int lane = threadIdx.x & 31;
  const int group = threadIdx.x >> 5;
  const int j0 = lane * 4;
  const int nb = (n_nodes + 7) >> 3;
  for (int batch = blockIdx.x; batch < nb; batch += gridDim.x) {
    int node = batch * 8 + group;
    if (node >= n_nodes) continue;
    const float4 hreg =
        reinterpret_cast<const float4*>(h + (size_t)node * HIDDEN)[lane];
    const float* hv = reinterpret_cast<const float*>(&hreg);
    float4 o = {0.f, 0.f, 0.f, 0.f};
#pragma unroll
    for (int k = 0; k < HIDDEN; ++k) {
      float a = __shfl(hv[k & 3], k >> 2, 32);
      float4 w = *reinterpret_cast<const float4*>(&Wt[k][j0]);
      o.x = fmaf(a, w.x, o.x);
      o.y = fmaf(a, w.y, o.y);
      o.z = fmaf(a, w.z, o.z);
      o.w = fmaf(a, w.w, o.w);
    }
    ushort4 u;
    u.x = f2bf(o.x);
    u.y = f2bf(o.y);
    u.z = f2bf(o.z);
    u.w = f2bf(o.w);
    *reinterpret_cast<ushort4*>(hW + (size_t)node * HIDDEN + j0) = u;
  }
}

// ---------------------------------------------------------------------------
// out[i] = deg>0 ? sum(hW[src]) + b : h[i].  16 lanes/node, no LDS.
// ---------------------------------------------------------------------------
__global__ void __launch_bounds__(256) gather_sum_kernel(
    const ushort* __restrict__ hW, const float* __restrict__ h,
    const float* __restrict__ b, const int* __restrict__ counts,
    const int* __restrict__ ends, const int* __restrict__ esorted,
    float* __restrict__ out, int n_nodes) {
  const int lane = threadIdx.x & 15;
  const int group = threadIdx.x >> 4;
  const int f0 = lane * 8;
  const int node = blockIdx.x * 16 + group;
  if (node >= n_nodes) return;

  const int deg = counts[node];
  float4 o0, o1;
  if (deg == 0) {
    o0 = *reinterpret_cast<const float4*>(h + (size_t)node * HIDDEN + f0);
    o1 = *reinterpret_cast<const float4*>(h + (size_t)node * HIDDEN + f0 + 4);
  } else {
    const int start = ends[node] - deg;
    float4 A = {0.f, 0.f, 0.f, 0.f};
    float4 B = {0.f, 0.f, 0.f, 0.f};
    for (int base = 0; base < deg; base += 16) {
      int sreg = 0;
      if (base + lane < deg) sreg = esorted[start + base + lane];
      const int m = min(16, deg - base);
#pragma unroll 4
      for (int jj = 0; jj < m; ++jj) {
        int s = __shfl(sreg, jj, 16);
        uint4 v =
            *reinterpret_cast<const uint4*>(hW + (size_t)s * HIDDEN + f0);
        A.x += __uint_as_float(v.x << 16);
        A.y += __uint_as_float(v.x & 0xffff0000u);
        A.z += __uint_as_float(v.y << 16);
        A.w += __uint_as_float(v.y & 0xffff0000u);
        B.x += __uint_as_float(v.z << 16);
        B.y += __uint_as_float(v.z & 0xffff0000u);
        B.z += __uint_as_float(v.w << 16);
        B.w += __uint_as_float(v.w & 0xffff0000u);
      }
    }
    const float4 b0 = *reinterpret_cast<const float4*>(b + f0);
    const float4 b1 = *reinterpret_cast<const float4*>(b + f0 + 4);
    o0 = {A.x + b0.x, A.y + b0.y, A.z + b0.z, A.w + b0.w};
    o1 = {B.x + b1.x, B.y + b1.y, B.z + b1.z, B.w + b1.w};
  }
  *reinterpret_cast<float4*>(out + (size_t)node * HIDDEN + f0) = o0;
  *reinterpret_cast<float4*>(out + (size_t)node * HIDDEN + f0 + 4) = o1;
}

// ---------------------------------------------------------------------------
// Fallback (ws too small for hW): R1 fused CSR path.
// ---------------------------------------------------------------------------

__global__ void __launch_bounds__(1024) scan_kernel(
    const int* __restrict__ counts, int* __restrict__ offsets, int n) {
  __shared__ int part[1024];
  const int t = threadIdx.x;
  const int C = (n + 1023) / 1024;
  const int base = t * C;
  int sum = 0;
  for (int j = 0; j < C; ++j) {
    int idx = base + j;
    if (idx < n) sum += counts[idx];
  }
  part[t] = sum;
  __syncthreads();
  for (int s = 1; s < 1024; s <<= 1) {
    int v = (t >= s) ? part[t - s] : 0;
    __syncthreads();
    part[t] += v;
    __syncthreads();
  }
  int run = part[t] - sum;
  for (int j = 0; j < C; ++j) {
    int idx = base + j;
    if (idx < n) {
      offsets[idx] = run;
      run += counts[idx];
    }
  }
}

__global__ void __launch_bounds__(256, 2) gather_update_kernel(
    const float* __restrict__ h, const float* __restrict__ W,
    const float* __restrict__ b, const int* __restrict__ counts,
    const int* __restrict__ ends, const int* __restrict__ esorted,
    float* __restrict__ out, int n_nodes) {
  __shared__ float Wt[HIDDEN][HIDDEN];
  for (int i = threadIdx.x; i < HIDDEN * HIDDEN / 4; i += 256) {
    int idx = i * 4;
    int j = idx >> 7;
    int k = idx & 127;
    float4 w = *reinterpret_cast<const float4*>(W + j * HIDDEN + k);
    Wt[k + 0][j] = w.x;
    Wt[k + 1][j] = w.y;
    Wt[k + 2][j] = w.z;
    Wt[k + 3][j] = w.w;
  }
  __syncthreads();
  const int lane = threadIdx.x & 31;
  const int group = threadIdx.x >> 5;
  const int j0 = lane * 4;
  const float4 bias = *reinterpret_cast<const float4*>(b + j0);
  const int nb = (n_nodes + 7) >> 3;
  for (int batch = blockIdx.x; batch < nb; batch += gridDim.x) {
    int node = batch * 8 + group;
    if (node >= n_nodes) continue;
    const int deg = counts[node];
    float4 res;
    if (deg == 0) {
      res = reinterpret_cast<const float4*>(h + (size_t)node * HIDDEN)[lane];
    } else {
      const int start = ends[node] - deg;
      float4 acc = {0.f, 0.f, 0.f, 0.f};
      for (int basei = 0; basei < deg; basei += 32) {
        int sreg = 0;
        if (basei + lane < deg) sreg = esorted[start + basei + lane];
        const int m = min(32, deg - basei);
        for (int jj = 0; jj < m; ++jj) {
          int s = __shfl(sreg, jj, 32);
          float4 v =
              reinterpret_cast<const float4*>(h + (size_t)s * HIDDEN)[lane];
          acc.x += v.x;
          acc.y += v.y;
          acc.z += v.z;
          acc.w += v.w;
        }
      }
      const float* av = reinterpret_cast<const float*>(&acc);
      float4 o = bias;
#pragma unroll
      for (int k = 0; k < HIDDEN; ++k) {
        float aval = __shfl(av[k & 3], k >> 2, 32);
        float4 w = *reinterpret_cast<const float4*>(&Wt[k][j0]);
        o.x = fmaf(aval, w.x, o.x);
        o.y = fmaf(aval, w.y, o.y);
        o.z = fmaf(aval, w.z, o.z);
        o.w = fmaf(aval, w.w, o.w);
      }
      res = o;
    }
    reinterpret_cast<float4*>(out + (size_t)node * HIDDEN)[lane] = res;
  }
}

// ---------------------------------------------------------------------------

extern "C" void kernel_launch(void* const* d_in, const int* in_sizes, int n_in,
                              void* d_out, int out_size, void* d_ws, size_t ws_size,
                              hipStream_t stream) {
  const float* h = (const float*)d_in[0];
  const float* W = (const float*)d_in[1];
  const float* b = (const float*)d_in[2];
  const int* src = (const int*)d_in[3];
  const int* dst = (const int*)d_in[4];
  float* out = (float*)d_out;
  const int n_nodes = in_sizes[0] / HIDDEN;
  const int n_edges = in_sizes[3];

  const int n_round = (n_nodes + 1023) & ~1023;  // multiple of 1024
  const int nt = n_round / 1024;                 // tiles for scan
  const int eblocks = (n_edges + 255) / 256;

  // ws layout: counts | offsets | tilesums(64) | esorted | hW(bf16)
  int* counts = (int*)d_ws;
  int* offsets = counts + n_round;
  int* tilesums = offsets + n_round;
  int* esorted = tilesums + 64;
  ushort* hW = (ushort*)(esorted + n_edges);
  const size_t need_csr = (size_t)(2 * n_round + 64 + n_edges) * sizeof(int);
  const size_t need_full =
      need_csr + (size_t)n_nodes * HIDDEN * sizeof(ushort);

  if (ws_size >= need_full && nt <= 64) {
    hipMemsetAsync(counts, 0, (size_t)n_nodes * sizeof(int), stream);
    hist_kernel<<<eblocks, 256, 0, stream>>>(dst, counts, n_edges);
    scanA_kernel<<<nt, 256, 0, stream>>>(counts, tilesums, n_nodes);
    scanB_kernel<<<1, 64, 0, stream>>>(tilesums, nt);
    scanC_kernel<<<nt, 256, 0, stream>>>(counts, tilesums, offsets, n_nodes);
    fill_kernel<<<eblocks, 256, 0, stream>>>(src, dst, offsets, esorted,
                                             n_edges);
    transform_kernel<<<512, 256, 0, stream>>>(h, W, hW, n_nodes);
    const int gblocks = (n_nodes + 15) / 16;
    gather_sum_kernel<<<gblocks, 256, 0, stream>>>(hW, h, b, counts, offsets,
                                                   esorted, out, n_nodes);
  } else {
    // Fallback: R1 fused CSR path (ws >= need_csr established empirically).
    hipMemsetAsync(counts, 0, (size_t)n_nodes * sizeof(int), stream);
    hist_kernel<<<eblocks, 256, 0, stream>>>(dst, counts, n_edges);
    scan_kernel<<<1, 1024, 0, stream>>>(counts, offsets, n_nodes);
    fill_kernel<<<eblocks, 256, 0, stream>>>(src, dst, offsets, esorted,
                                             n_edges);
    gather_update_kernel<<<512, 256, 0, stream>>>(h, W, b, counts, offsets,
                                                  esorted, out, n_nodes);
  }
}

// Round 5
// 186.260 us; speedup vs baseline: 7.0529x; 1.2501x over previous
//
#include <hip/hip_runtime.h>
#include <hip/hip_bf16.h>

static constexpr int HIDDEN = 128;

using bf16x8 = __attribute__((ext_vector_type(8))) __bf16;
using f32x4 = __attribute__((ext_vector_type(4))) float;

__device__ inline ushort f2bf(float x) {
  __hip_bfloat16 t = __float2bfloat16(x);
  return *reinterpret_cast<ushort*>(&t);
}

// ---------------------------------------------------------------------------
// CSR build: hist -> 3-phase parallel scan -> fill
// ---------------------------------------------------------------------------

__global__ void __launch_bounds__(256) hist_kernel(
    const int* __restrict__ dst, int* __restrict__ counts, int n_edges) {
  int i = blockIdx.x * 256 + threadIdx.x;
  if (i < n_edges) atomicAdd(&counts[dst[i]], 1);
}

// Phase A: per-tile (1024 elements) sums.
__global__ void __launch_bounds__(256) scanA_kernel(
    const int* __restrict__ counts, int* __restrict__ tilesums, int n) {
  const int t = threadIdx.x;
  const int base = blockIdx.x * 1024 + t * 4;
  int s = 0;
  if (base + 3 < n) {
    int4 v = *reinterpret_cast<const int4*>(counts + base);
    s = v.x + v.y + v.z + v.w;
  } else {
    for (int j = 0; j < 4; ++j)
      if (base + j < n) s += counts[base + j];
  }
  for (int off = 1; off < 64; off <<= 1) s += __shfl_xor(s, off, 64);
  __shared__ int wp[4];
  if ((t & 63) == 0) wp[t >> 6] = s;
  __syncthreads();
  if (t == 0) tilesums[blockIdx.x] = wp[0] + wp[1] + wp[2] + wp[3];
}

// Phase B: exclusive scan of <=64 tile sums, one wave.
__global__ void __launch_bounds__(64) scanB_kernel(int* tilesums, int nt) {
  int t = threadIdx.x;
  int v = (t < nt) ? tilesums[t] : 0;
  int orig = v;
  for (int off = 1; off < 64; off <<= 1) {
    int u = __shfl_up(v, off, 64);
    if (t >= off) v += u;
  }
  if (t < nt) tilesums[t] = v - orig;
}

// Phase C: write exclusive offsets.
__global__ void __launch_bounds__(256) scanC_kernel(
    const int* __restrict__ counts, const int* __restrict__ tileprefix,
    int* __restrict__ offsets, int n) {
  const int t = threadIdx.x;
  const int base = blockIdx.x * 1024 + t * 4;
  int4 v = {0, 0, 0, 0};
  const bool full = (base + 3 < n);
  if (full) {
    v = *reinterpret_cast<const int4*>(counts + base);
  } else {
    if (base + 0 < n) v.x = counts[base + 0];
    if (base + 1 < n) v.y = counts[base + 1];
    if (base + 2 < n) v.z = counts[base + 2];
    if (base + 3 < n) v.w = counts[base + 3];
  }
  const int s = v.x + v.y + v.z + v.w;
  int inc = s;
  for (int off = 1; off < 64; off <<= 1) {
    int u = __shfl_up(inc, off, 64);
    if ((t & 63) >= off) inc += u;
  }
  const int excl = inc - s;
  __shared__ int wp[4];
  if ((t & 63) == 63) wp[t >> 6] = inc;
  __syncthreads();
  int wbase = 0;
  for (int w = 0; w < (t >> 6); ++w) wbase += wp[w];
  int p = tileprefix[blockIdx.x] + wbase + excl;
  if (full) {
    int4 o;
    o.x = p;
    o.y = p + v.x;
    o.z = p + v.x + v.y;
    o.w = p + v.x + v.y + v.z;
    *reinterpret_cast<int4*>(offsets + base) = o;
  } else {
    int run = p;
    if (base + 0 < n) { offsets[base + 0] = run; run += v.x; }
    if (base + 1 < n) { offsets[base + 1] = run; run += v.y; }
    if (base + 2 < n) { offsets[base + 2] = run; run += v.z; }
    if (base + 3 < n) { offsets[base + 3] = run; }
  }
}

// offsets doubles as the fill cursor; afterwards offsets[d] == end_d.
__global__ void __launch_bounds__(256) fill_kernel(
    const int* __restrict__ src, const int* __restrict__ dst,
    int* __restrict__ offsets, int* __restrict__ esorted, int n_edges) {
  int i = blockIdx.x * 256 + threadIdx.x;
  if (i < n_edges) {
    int pos = atomicAdd(&offsets[dst[i]], 1);
    esorted[pos] = src[i];
  }
}

// ---------------------------------------------------------------------------
// W (fp32 [128][128]) -> bf16, row-major unchanged. 16384 elements.
// ---------------------------------------------------------------------------
__global__ void __launch_bounds__(256) wconv_kernel(
    const float* __restrict__ W, ushort* __restrict__ wbf) {
  int i = blockIdx.x * 256 + threadIdx.x;
  if (i < HIDDEN * HIDDEN) wbf[i] = f2bf(W[i]);
}

// ---------------------------------------------------------------------------
// hW = bf16(h) @ bf16(W).T via MFMA 16x16x32. No LDS.
// Block = 4 waves; wave handles 16 node-rows x 128 cols.
// A frag: lane reads h[base + (lane&15)][ks*32 + (lane>>4)*8 ..+7] (fp32->bf16).
// B frag: lane reads wbf row (ct*16 + (lane&15)), same k slice -- contiguous
//         16B, no transpose needed since out = h @ W^T.
// D: lane holds C[(lane>>4)*4 + r][lane&15], r=0..3.
// ---------------------------------------------------------------------------
__global__ void __launch_bounds__(256) transform_mfma_kernel(
    const float* __restrict__ h, const ushort* __restrict__ wbf,
    ushort* __restrict__ hW, int n_nodes) {
  const int wave = threadIdx.x >> 6;
  const int lane = threadIdx.x & 63;
  const int r16 = lane & 15;
  const int kq = lane >> 4;       // 0..3
  const int kbase = kq * 8;
  const int base = blockIdx.x * 64 + wave * 16;

  int arow = base + r16;
  if (arow >= n_nodes) arow = n_nodes - 1;  // clamp (loads only)
  const float* hrow = h + (size_t)arow * HIDDEN;

  bf16x8 a[4];
#pragma unroll
  for (int ks = 0; ks < 4; ++ks) {
    const float4 u = *reinterpret_cast<const float4*>(hrow + ks * 32 + kbase);
    const float4 v =
        *reinterpret_cast<const float4*>(hrow + ks * 32 + kbase + 4);
    bf16x8 t;
    t[0] = (__bf16)u.x;
    t[1] = (__bf16)u.y;
    t[2] = (__bf16)u.z;
    t[3] = (__bf16)u.w;
    t[4] = (__bf16)v.x;
    t[5] = (__bf16)v.y;
    t[6] = (__bf16)v.z;
    t[7] = (__bf16)v.w;
    a[ks] = t;
  }

  const int drow0 = base + kq * 4;
#pragma unroll
  for (int ct = 0; ct < 8; ++ct) {
    const ushort* wrow = wbf + (size_t)(ct * 16 + r16) * HIDDEN;
    f32x4 acc = {0.f, 0.f, 0.f, 0.f};
#pragma unroll
    for (int ks = 0; ks < 4; ++ks) {
      bf16x8 bfrag =
          *reinterpret_cast<const bf16x8*>(wrow + ks * 32 + kbase);
      acc = __builtin_amdgcn_mfma_f32_16x16x32_bf16(a[ks], bfrag, acc, 0, 0, 0);
    }
#pragma unroll
    for (int r = 0; r < 4; ++r) {
      int nrow = drow0 + r;
      if (nrow < n_nodes)
        hW[(size_t)nrow * HIDDEN + ct * 16 + r16] = f2bf(acc[r]);
    }
  }
}

// ---------------------------------------------------------------------------
// out[i] = deg>0 ? sum(hW[src]) + b : h[i].  16 lanes/node, no LDS.
// ---------------------------------------------------------------------------
__global__ void __launch_bounds__(256) gather_sum_kernel(
    const ushort* __restrict__ hW, const float* __restrict__ h,
    const float* __restrict__ b, const int* __restrict__ counts,
    const int* __restrict__ ends, const int* __restrict__ esorted,
    float* __restrict__ out, int n_nodes) {
  const int lane = threadIdx.x & 15;
  const int group = threadIdx.x >> 4;
  const int f0 = lane * 8;
  const int node = blockIdx.x * 16 + group;
  if (node >= n_nodes) return;

  const int deg = counts[node];
  float4 o0, o1;
  if (deg == 0) {
    o0 = *reinterpret_cast<const float4*>(h + (size_t)node * HIDDEN + f0);
    o1 = *reinterpret_cast<const float4*>(h + (size_t)node * HIDDEN + f0 + 4);
  } else {
    const int start = ends[node] - deg;
    float4 A = {0.f, 0.f, 0.f, 0.f};
    float4 B = {0.f, 0.f, 0.f, 0.f};
    for (int base = 0; base < deg; base += 16) {
      int sreg = 0;
      if (base + lane < deg) sreg = esorted[start + base + lane];
      const int m = min(16, deg - base);
#pragma unroll 8
      for (int jj = 0; jj < m; ++jj) {
        int s = __shfl(sreg, jj, 16);
        uint4 v =
            *reinterpret_cast<const uint4*>(hW + (size_t)s * HIDDEN + f0);
        A.x += __uint_as_float(v.x << 16);
        A.y += __uint_as_float(v.x & 0xffff0000u);
        A.z += __uint_as_float(v.y << 16);
        A.w += __uint_as_float(v.y & 0xffff0000u);
        B.x += __uint_as_float(v.z << 16);
        B.y += __uint_as_float(v.z & 0xffff0000u);
        B.z += __uint_as_float(v.w << 16);
        B.w += __uint_as_float(v.w & 0xffff0000u);
      }
    }
    const float4 b0 = *reinterpret_cast<const float4*>(b + f0);
    const float4 b1 = *reinterpret_cast<const float4*>(b + f0 + 4);
    o0 = {A.x + b0.x, A.y + b0.y, A.z + b0.z, A.w + b0.w};
    o1 = {B.x + b1.x, B.y + b1.y, B.z + b1.z, B.w + b1.w};
  }
  *reinterpret_cast<float4*>(out + (size_t)node * HIDDEN + f0) = o0;
  *reinterpret_cast<float4*>(out + (size_t)node * HIDDEN + f0 + 4) = o1;
}

// ---------------------------------------------------------------------------
// Fallback (ws too small): R1 fused CSR path.
// ---------------------------------------------------------------------------

__global__ void __launch_bounds__(1024) scan_kernel(
    const int* __restrict__ counts, int* __restrict__ offsets, int n) {
  __shared__ int part[1024];
  const int t = threadIdx.x;
  const int C = (n + 1023) / 1024;
  const int base = t * C;
  int sum = 0;
  for (int j = 0; j < C; ++j) {
    int idx = base + j;
    if (idx < n) sum += counts[idx];
  }
  part[t] = sum;
  __syncthreads();
  for (int s = 1; s < 1024; s <<= 1) {
    int v = (t >= s) ? part[t - s] : 0;
    __syncthreads();
    part[t] += v;
    __syncthreads();
  }
  int run = part[t] - sum;
  for (int j = 0; j < C; ++j) {
    int idx = base + j;
    if (idx < n) {
      offsets[idx] = run;
      run += counts[idx];
    }
  }
}

__global__ void __launch_bounds__(256, 2) gather_update_kernel(
    const float* __restrict__ h, const float* __restrict__ W,
    const float* __restrict__ b, const int* __restrict__ counts,
    const int* __restrict__ ends, const int* __restrict__ esorted,
    float* __restrict__ out, int n_nodes) {
  __shared__ float Wt[HIDDEN][HIDDEN];
  for (int i = threadIdx.x; i < HIDDEN * HIDDEN / 4; i += 256) {
    int idx = i * 4;
    int j = idx >> 7;
    int k = idx & 127;
    float4 w = *reinterpret_cast<const float4*>(W + j * HIDDEN + k);
    Wt[k + 0][j] = w.x;
    Wt[k + 1][j] = w.y;
    Wt[k + 2][j] = w.z;
    Wt[k + 3][j] = w.w;
  }
  __syncthreads();
  const int lane = threadIdx.x & 31;
  const int group = threadIdx.x >> 5;
  const int j0 = lane * 4;
  const float4 bias = *reinterpret_cast<const float4*>(b + j0);
  const int nb = (n_nodes + 7) >> 3;
  for (int batch = blockIdx.x; batch < nb; batch += gridDim.x) {
    int node = batch * 8 + group;
    if (node >= n_nodes) continue;
    const int deg = counts[node];
    float4 res;
    if (deg == 0) {
      res = reinterpret_cast<const float4*>(h + (size_t)node * HIDDEN)[lane];
    } else {
      const int start = ends[node] - deg;
      float4 acc = {0.f, 0.f, 0.f, 0.f};
      for (int basei = 0; basei < deg; basei += 32) {
        int sreg = 0;
        if (basei + lane < deg) sreg = esorted[start + basei + lane];
        const int m = min(32, deg - basei);
        for (int jj = 0; jj < m; ++jj) {
          int s = __shfl(sreg, jj, 32);
          float4 v =
              reinterpret_cast<const float4*>(h + (size_t)s * HIDDEN)[lane];
          acc.x += v.x;
          acc.y += v.y;
          acc.z += v.z;
          acc.w += v.w;
        }
      }
      const float* av = reinterpret_cast<const float*>(&acc);
      float4 o = bias;
#pragma unroll
      for (int k = 0; k < HIDDEN; ++k) {
        float aval = __shfl(av[k & 3], k >> 2, 32);
        float4 w = *reinterpret_cast<const float4*>(&Wt[k][j0]);
        o.x = fmaf(aval, w.x, o.x);
        o.y = fmaf(aval, w.y, o.y);
        o.z = fmaf(aval, w.z, o.z);
        o.w = fmaf(aval, w.w, o.w);
      }
      res = o;
    }
    reinterpret_cast<float4*>(out + (size_t)node * HIDDEN)[lane] = res;
  }
}

// ---------------------------------------------------------------------------

extern "C" void kernel_launch(void* const* d_in, const int* in_sizes, int n_in,
                              void* d_out, int out_size, void* d_ws, size_t ws_size,
                              hipStream_t stream) {
  const float* h = (const float*)d_in[0];
  const float* W = (const float*)d_in[1];
  const float* b = (const float*)d_in[2];
  const int* src = (const int*)d_in[3];
  const int* dst = (const int*)d_in[4];
  float* out = (float*)d_out;
  const int n_nodes = in_sizes[0] / HIDDEN;
  const int n_edges = in_sizes[3];

  const int n_round = (n_nodes + 1023) & ~1023;  // multiple of 1024
  const int nt = n_round / 1024;                 // tiles for scan
  const int eblocks = (n_edges + 255) / 256;

  // ws layout (ints): counts | offsets | tilesums(64) | esorted | hW | wbf
  int* counts = (int*)d_ws;
  int* offsets = counts + n_round;
  int* tilesums = offsets + n_round;
  int* esorted = tilesums + 64;
  // 16B-align the bf16 regions.
  size_t off_bytes = ((size_t)(2 * n_round + 64 + n_edges) * 4 + 15) & ~15ull;
  ushort* hW = (ushort*)((char*)d_ws + off_bytes);
  size_t wbf_off =
      (off_bytes + (size_t)n_nodes * HIDDEN * 2 + 15) & ~15ull;
  ushort* wbf = (ushort*)((char*)d_ws + wbf_off);
  const size_t need_full = wbf_off + (size_t)HIDDEN * HIDDEN * 2;

  if (ws_size >= need_full && nt <= 64) {
    hipMemsetAsync(counts, 0, (size_t)n_nodes * sizeof(int), stream);
    hist_kernel<<<eblocks, 256, 0, stream>>>(dst, counts, n_edges);
    scanA_kernel<<<nt, 256, 0, stream>>>(counts, tilesums, n_nodes);
    scanB_kernel<<<1, 64, 0, stream>>>(tilesums, nt);
    scanC_kernel<<<nt, 256, 0, stream>>>(counts, tilesums, offsets, n_nodes);
    fill_kernel<<<eblocks, 256, 0, stream>>>(src, dst, offsets, esorted,
                                             n_edges);
    wconv_kernel<<<(HIDDEN * HIDDEN + 255) / 256, 256, 0, stream>>>(W, wbf);
    const int tblocks = (n_nodes + 63) / 64;
    transform_mfma_kernel<<<tblocks, 256, 0, stream>>>(h, wbf, hW, n_nodes);
    const int gblocks = (n_nodes + 15) / 16;
    gather_sum_kernel<<<gblocks, 256, 0, stream>>>(hW, h, b, counts, offsets,
                                                   esorted, out, n_nodes);
  } else {
    // Fallback: R1 fused CSR path.
    hipMemsetAsync(counts, 0, (size_t)n_nodes * sizeof(int), stream);
    hist_kernel<<<eblocks, 256, 0, stream>>>(dst, counts, n_edges);
    scan_kernel<<<1, 1024, 0, stream>>>(counts, offsets, n_nodes);
    fill_kernel<<<eblocks, 256, 0, stream>>>(src, dst, offsets, esorted,
                                             n_edges);
    gather_update_kernel<<<512, 256, 0, stream>>>(h, W, b, counts, offsets,
                                                  esorted, out, n_nodes);
  }
}

// Round 7
// 184.029 us; speedup vs baseline: 7.1384x; 1.0121x over previous
//
#include <hip/hip_runtime.h>
#include <hip/hip_bf16.h>

static constexpr int HIDDEN = 128;

using bf16x8 = __attribute__((ext_vector_type(8))) __bf16;
using f32x4 = __attribute__((ext_vector_type(4))) float;
using ushort8v = __attribute__((ext_vector_type(8))) ushort;

__device__ inline ushort f2bf(float x) {
  __hip_bfloat16 t = __float2bfloat16(x);
  return *reinterpret_cast<ushort*>(&t);
}

// ---------------------------------------------------------------------------
// hist (4 edges/thread) fused with wconv (W fp32 -> bf16) on trailing blocks.
// ---------------------------------------------------------------------------
__global__ void __launch_bounds__(256) hist_wconv_kernel(
    const int* __restrict__ dst, int* __restrict__ counts, int n_edges,
    int nbh, const float* __restrict__ W, ushort* __restrict__ wbf) {
  if (blockIdx.x < nbh) {
    int i = (blockIdx.x * 256 + threadIdx.x) * 4;
    if (i + 3 < n_edges) {
      int4 d = *reinterpret_cast<const int4*>(dst + i);
      atomicAdd(&counts[d.x], 1);
      atomicAdd(&counts[d.y], 1);
      atomicAdd(&counts[d.z], 1);
      atomicAdd(&counts[d.w], 1);
    } else {
      for (int j = i; j < n_edges; ++j) atomicAdd(&counts[dst[j]], 1);
    }
  } else {
    int i = ((blockIdx.x - nbh) * 256 + threadIdx.x) * 4;
    if (i < HIDDEN * HIDDEN) {
      float4 w = *reinterpret_cast<const float4*>(W + i);
      ushort4 u;
      u.x = f2bf(w.x);
      u.y = f2bf(w.y);
      u.z = f2bf(w.z);
      u.w = f2bf(w.w);
      *reinterpret_cast<ushort4*>(wbf + i) = u;
    }
  }
}

// Phase A: per-tile (1024 elements) sums.
__global__ void __launch_bounds__(256) scanA_kernel(
    const int* __restrict__ counts, int* __restrict__ tilesums, int n) {
  const int t = threadIdx.x;
  const int base = blockIdx.x * 1024 + t * 4;
  int s = 0;
  if (base + 3 < n) {
    int4 v = *reinterpret_cast<const int4*>(counts + base);
    s = v.x + v.y + v.z + v.w;
  } else {
    for (int j = 0; j < 4; ++j)
      if (base + j < n) s += counts[base + j];
  }
  for (int off = 1; off < 64; off <<= 1) s += __shfl_xor(s, off, 64);
  __shared__ int wp[4];
  if ((t & 63) == 0) wp[t >> 6] = s;
  __syncthreads();
  if (t == 0) tilesums[blockIdx.x] = wp[0] + wp[1] + wp[2] + wp[3];
}

// Phase C (fused with B): every block wave-scans the <=64 tile sums, then
// writes exclusive offsets for its tile.
__global__ void __launch_bounds__(256) scanC_kernel(
    const int* __restrict__ counts, const int* __restrict__ tilesums,
    int* __restrict__ offsets, int n, int nt) {
  __shared__ int tp[64];
  const int t = threadIdx.x;
  if (t < 64) {
    int v = (t < nt) ? tilesums[t] : 0;
    int orig = v;
    for (int off = 1; off < 64; off <<= 1) {
      int u = __shfl_up(v, off, 64);
      if (t >= off) v += u;
    }
    tp[t] = v - orig;  // exclusive prefix of tiles
  }
  __syncthreads();

  const int base = blockIdx.x * 1024 + t * 4;
  int4 v = {0, 0, 0, 0};
  const bool full = (base + 3 < n);
  if (full) {
    v = *reinterpret_cast<const int4*>(counts + base);
  } else {
    if (base + 0 < n) v.x = counts[base + 0];
    if (base + 1 < n) v.y = counts[base + 1];
    if (base + 2 < n) v.z = counts[base + 2];
    if (base + 3 < n) v.w = counts[base + 3];
  }
  const int s = v.x + v.y + v.z + v.w;
  int inc = s;
  for (int off = 1; off < 64; off <<= 1) {
    int u = __shfl_up(inc, off, 64);
    if ((t & 63) >= off) inc += u;
  }
  const int excl = inc - s;
  __shared__ int wp[4];
  if ((t & 63) == 63) wp[t >> 6] = inc;
  __syncthreads();
  int wbase = 0;
  for (int w = 0; w < (t >> 6); ++w) wbase += wp[w];
  int p = tp[blockIdx.x] + wbase + excl;
  if (full) {
    int4 o;
    o.x = p;
    o.y = p + v.x;
    o.z = p + v.x + v.y;
    o.w = p + v.x + v.y + v.z;
    *reinterpret_cast<int4*>(offsets + base) = o;
  } else {
    int run = p;
    if (base + 0 < n) { offsets[base + 0] = run; run += v.x; }
    if (base + 1 < n) { offsets[base + 1] = run; run += v.y; }
    if (base + 2 < n) { offsets[base + 2] = run; run += v.z; }
    if (base + 3 < n) { offsets[base + 3] = run; }
  }
}

// offsets doubles as the fill cursor; afterwards offsets[d] == end_d.
// 4 edges/thread.
__global__ void __launch_bounds__(256) fill_kernel(
    const int* __restrict__ src, const int* __restrict__ dst,
    int* __restrict__ offsets, int* __restrict__ esorted, int n_edges) {
  int i = (blockIdx.x * 256 + threadIdx.x) * 4;
  if (i + 3 < n_edges) {
    int4 s = *reinterpret_cast<const int4*>(src + i);
    int4 d = *reinterpret_cast<const int4*>(dst + i);
    int p0 = atomicAdd(&offsets[d.x], 1);
    int p1 = atomicAdd(&offsets[d.y], 1);
    int p2 = atomicAdd(&offsets[d.z], 1);
    int p3 = atomicAdd(&offsets[d.w], 1);
    esorted[p0] = s.x;
    esorted[p1] = s.y;
    esorted[p2] = s.z;
    esorted[p3] = s.w;
  } else {
    for (int j = i; j < n_edges; ++j) {
      int pos = atomicAdd(&offsets[dst[j]], 1);
      esorted[pos] = src[j];
    }
  }
}

// ---------------------------------------------------------------------------
// hW = bf16(h) @ bf16(W).T via MFMA 16x16x32. LDS only as store-stage.
// Wave: 16 node-rows x 128 cols. D layout: col=lane&15, row=(lane>>4)*4+r.
// Epilogue: stage D tile in LDS (padded 136 cols -> 16B-aligned rows), then
// packed ushort8 (16B) coalesced stores.
// ---------------------------------------------------------------------------
__global__ void __launch_bounds__(256) transform_mfma_kernel(
    const float* __restrict__ h, const ushort* __restrict__ wbf,
    ushort* __restrict__ hW, int n_nodes) {
  constexpr int COLP = 136;  // pad: 272B row stride, 16B aligned
  __shared__ ushort tile[4][16][COLP];
  const int wave = threadIdx.x >> 6;
  const int lane = threadIdx.x & 63;
  const int r16 = lane & 15;
  const int kq = lane >> 4;  // 0..3
  const int kbase = kq * 8;
  const int base = blockIdx.x * 64 + wave * 16;

  int arow = base + r16;
  if (arow >= n_nodes) arow = n_nodes - 1;  // clamp (loads only)
  const float* hrow = h + (size_t)arow * HIDDEN;

  bf16x8 a[4];
#pragma unroll
  for (int ks = 0; ks < 4; ++ks) {
    const float4 u = *reinterpret_cast<const float4*>(hrow + ks * 32 + kbase);
    const float4 v =
        *reinterpret_cast<const float4*>(hrow + ks * 32 + kbase + 4);
    bf16x8 t;
    t[0] = (__bf16)u.x;
    t[1] = (__bf16)u.y;
    t[2] = (__bf16)u.z;
    t[3] = (__bf16)u.w;
    t[4] = (__bf16)v.x;
    t[5] = (__bf16)v.y;
    t[6] = (__bf16)v.z;
    t[7] = (__bf16)v.w;
    a[ks] = t;
  }

#pragma unroll
  for (int ct = 0; ct < 8; ++ct) {
    const ushort* wrow = wbf + (size_t)(ct * 16 + r16) * HIDDEN;
    f32x4 acc = {0.f, 0.f, 0.f, 0.f};
#pragma unroll
    for (int ks = 0; ks < 4; ++ks) {
      bf16x8 bfrag = *reinterpret_cast<const bf16x8*>(wrow + ks * 32 + kbase);
      acc = __builtin_amdgcn_mfma_f32_16x16x32_bf16(a[ks], bfrag, acc, 0, 0, 0);
    }
#pragma unroll
    for (int r = 0; r < 4; ++r)
      tile[wave][kq * 4 + r][ct * 16 + r16] = f2bf(acc[r]);
  }
  // Wave-local LDS roundtrip: compiler orders via lgkmcnt; no barrier needed
  // (each wave touches only tile[wave]).
#pragma unroll
  for (int it = 0; it < 4; ++it) {
    const int row = it * 4 + (lane >> 4);
    const int cb = r16 * 8;
    const int nrow = base + row;
    if (nrow < n_nodes) {
      ushort8v v = *reinterpret_cast<const ushort8v*>(&tile[wave][row][cb]);
      *reinterpret_cast<ushort8v*>(hW + (size_t)nrow * HIDDEN + cb) = v;
    }
  }
}

// ---------------------------------------------------------------------------
// out[i] = deg>0 ? sum(hW[src]) + b : h[i].  16 lanes/node, no LDS.
// Nontemporal on esorted (read-once) and out (write-once) to keep L2 for hW.
// ---------------------------------------------------------------------------
__global__ void __launch_bounds__(256) gather_sum_kernel(
    const ushort* __restrict__ hW, const float* __restrict__ h,
    const float* __restrict__ b, const int* __restrict__ counts,
    const int* __restrict__ ends, const int* __restrict__ esorted,
    float* __restrict__ out, int n_nodes) {
  const int lane = threadIdx.x & 15;
  const int group = threadIdx.x >> 4;
  const int f0 = lane * 8;
  const int node = blockIdx.x * 16 + group;
  if (node >= n_nodes) return;

  const int deg = counts[node];
  f32x4 o0, o1;
  if (deg == 0) {
    float4 t0 = *reinterpret_cast<const float4*>(h + (size_t)node * HIDDEN + f0);
    float4 t1 =
        *reinterpret_cast<const float4*>(h + (size_t)node * HIDDEN + f0 + 4);
    o0 = {t0.x, t0.y, t0.z, t0.w};
    o1 = {t1.x, t1.y, t1.z, t1.w};
  } else {
    const int start = ends[node] - deg;
    float4 A = {0.f, 0.f, 0.f, 0.f};
    float4 B = {0.f, 0.f, 0.f, 0.f};
    for (int base = 0; base < deg; base += 16) {
      int sreg = 0;
      if (base + lane < deg)
        sreg = __builtin_nontemporal_load(esorted + start + base + lane);
      const int m = min(16, deg - base);
#pragma unroll 8
      for (int jj = 0; jj < m; ++jj) {
        int s = __shfl(sreg, jj, 16);
        uint4 v = *reinterpret_cast<const uint4*>(hW + (size_t)s * HIDDEN + f0);
        A.x += __uint_as_float(v.x << 16);
        A.y += __uint_as_float(v.x & 0xffff0000u);
        A.z += __uint_as_float(v.y << 16);
        A.w += __uint_as_float(v.y & 0xffff0000u);
        B.x += __uint_as_float(v.z << 16);
        B.y += __uint_as_float(v.z & 0xffff0000u);
        B.z += __uint_as_float(v.w << 16);
        B.w += __uint_as_float(v.w & 0xffff0000u);
      }
    }
    const float4 b0 = *reinterpret_cast<const float4*>(b + f0);
    const float4 b1 = *reinterpret_cast<const float4*>(b + f0 + 4);
    o0 = {A.x + b0.x, A.y + b0.y, A.z + b0.z, A.w + b0.w};
    o1 = {B.x + b1.x, B.y + b1.y, B.z + b1.z, B.w + b1.w};
  }
  __builtin_nontemporal_store(
      o0, reinterpret_cast<f32x4*>(out + (size_t)node * HIDDEN + f0));
  __builtin_nontemporal_store(
      o1, reinterpret_cast<f32x4*>(out + (size_t)node * HIDDEN + f0 + 4));
}

// ---------------------------------------------------------------------------
// Fallback (ws too small): R1 fused CSR path.
// ---------------------------------------------------------------------------

__global__ void __launch_bounds__(256) hist_kernel(
    const int* __restrict__ dst, int* __restrict__ counts, int n_edges) {
  int i = blockIdx.x * 256 + threadIdx.x;
  if (i < n_edges) atomicAdd(&counts[dst[i]], 1);
}

__global__ void __launch_bounds__(256) fill1_kernel(
    const int* __restrict__ src, const int* __restrict__ dst,
    int* __restrict__ offsets, int* __restrict__ esorted, int n_edges) {
  int i = blockIdx.x * 256 + threadIdx.x;
  if (i < n_edges) {
    int pos = atomicAdd(&offsets[dst[i]], 1);
    esorted[pos] = src[i];
  }
}

__global__ void __launch_bounds__(1024) scan_kernel(
    const int* __restrict__ counts, int* __restrict__ offsets, int n) {
  __shared__ int part[1024];
  const int t = threadIdx.x;
  const int C = (n + 1023) / 1024;
  const int base = t * C;
  int sum = 0;
  for (int j = 0; j < C; ++j) {
    int idx = base + j;
    if (idx < n) sum += counts[idx];
  }
  part[t] = sum;
  __syncthreads();
  for (int s = 1; s < 1024; s <<= 1) {
    int v = (t >= s) ? part[t - s] : 0;
    __syncthreads();
    part[t] += v;
    __syncthreads();
  }
  int run = part[t] - sum;
  for (int j = 0; j < C; ++j) {
    int idx = base + j;
    if (idx < n) {
      offsets[idx] = run;
      run += counts[idx];
    }
  }
}

__global__ void __launch_bounds__(256, 2) gather_update_kernel(
    const float* __restrict__ h, const float* __restrict__ W,
    const float* __restrict__ b, const int* __restrict__ counts,
    const int* __restrict__ ends, const int* __restrict__ esorted,
    float* __restrict__ out, int n_nodes) {
  __shared__ float Wt[HIDDEN][HIDDEN];
  for (int i = threadIdx.x; i < HIDDEN * HIDDEN / 4; i += 256) {
    int idx = i * 4;
    int j = idx >> 7;
    int k = idx & 127;
    float4 w = *reinterpret_cast<const float4*>(W + j * HIDDEN + k);
    Wt[k + 0][j] = w.x;
    Wt[k + 1][j] = w.y;
    Wt[k + 2][j] = w.z;
    Wt[k + 3][j] = w.w;
  }
  __syncthreads();
  const int lane = threadIdx.x & 31;
  const int group = threadIdx.x >> 5;
  const int j0 = lane * 4;
  const float4 bias = *reinterpret_cast<const float4*>(b + j0);
  const int nb = (n_nodes + 7) >> 3;
  for (int batch = blockIdx.x; batch < nb; batch += gridDim.x) {
    int node = batch * 8 + group;
    if (node >= n_nodes) continue;
    const int deg = counts[node];
    float4 res;
    if (deg == 0) {
      res = reinterpret_cast<const float4*>(h + (size_t)node * HIDDEN)[lane];
    } else {
      const int start = ends[node] - deg;
      float4 acc = {0.f, 0.f, 0.f, 0.f};
      for (int basei = 0; basei < deg; basei += 32) {
        int sreg = 0;
        if (basei + lane < deg) sreg = esorted[start + basei + lane];
        const int m = min(32, deg - basei);
        for (int jj = 0; jj < m; ++jj) {
          int s = __shfl(sreg, jj, 32);
          float4 v =
              reinterpret_cast<const float4*>(h + (size_t)s * HIDDEN)[lane];
          acc.x += v.x;
          acc.y += v.y;
          acc.z += v.z;
          acc.w += v.w;
        }
      }
      const float* av = reinterpret_cast<const float*>(&acc);
      float4 o = bias;
#pragma unroll
      for (int k = 0; k < HIDDEN; ++k) {
        float aval = __shfl(av[k & 3], k >> 2, 32);
        float4 w = *reinterpret_cast<const float4*>(&Wt[k][j0]);
        o.x = fmaf(aval, w.x, o.x);
        o.y = fmaf(aval, w.y, o.y);
        o.z = fmaf(aval, w.z, o.z);
        o.w = fmaf(aval, w.w, o.w);
      }
      res = o;
    }
    reinterpret_cast<float4*>(out + (size_t)node * HIDDEN)[lane] = res;
  }
}

// ---------------------------------------------------------------------------

extern "C" void kernel_launch(void* const* d_in, const int* in_sizes, int n_in,
                              void* d_out, int out_size, void* d_ws, size_t ws_size,
                              hipStream_t stream) {
  const float* h = (const float*)d_in[0];
  const float* W = (const float*)d_in[1];
  const float* b = (const float*)d_in[2];
  const int* src = (const int*)d_in[3];
  const int* dst = (const int*)d_in[4];
  float* out = (float*)d_out;
  const int n_nodes = in_sizes[0] / HIDDEN;
  const int n_edges = in_sizes[3];

  const int n_round = (n_nodes + 1023) & ~1023;  // multiple of 1024
  const int nt = n_round / 1024;                 // tiles for scan
  const int eblocks4 = (n_edges + 1023) / 1024;  // 4 edges/thread

  // ws layout (ints): counts | offsets | tilesums(64) | esorted | hW | wbf
  int* counts = (int*)d_ws;
  int* offsets = counts + n_round;
  int* tilesums = offsets + n_round;
  int* esorted = tilesums + 64;
  size_t off_bytes = ((size_t)(2 * n_round + 64 + n_edges) * 4 + 15) & ~15ull;
  ushort* hW = (ushort*)((char*)d_ws + off_bytes);
  size_t wbf_off = (off_bytes + (size_t)n_nodes * HIDDEN * 2 + 15) & ~15ull;
  ushort* wbf = (ushort*)((char*)d_ws + wbf_off);
  const size_t need_full = wbf_off + (size_t)HIDDEN * HIDDEN * 2;

  if (ws_size >= need_full && nt <= 64) {
    (void)hipMemsetAsync(counts, 0, (size_t)n_nodes * sizeof(int), stream);
    const int wblocks = (HIDDEN * HIDDEN + 1023) / 1024;
    hist_wconv_kernel<<<eblocks4 + wblocks, 256, 0, stream>>>(
        dst, counts, n_edges, eblocks4, W, wbf);
    scanA_kernel<<<nt, 256, 0, stream>>>(counts, tilesums, n_nodes);
    scanC_kernel<<<nt, 256, 0, stream>>>(counts, tilesums, offsets, n_nodes,
                                         nt);
    fill_kernel<<<eblocks4, 256, 0, stream>>>(src, dst, offsets, esorted,
                                              n_edges);
    const int tblocks = (n_nodes + 63) / 64;
    transform_mfma_kernel<<<tblocks, 256, 0, stream>>>(h, wbf, hW, n_nodes);
    const int gblocks = (n_nodes + 15) / 16;
    gather_sum_kernel<<<gblocks, 256, 0, stream>>>(hW, h, b, counts, offsets,
                                                   esorted, out, n_nodes);
  } else {
    // Fallback: R1 fused CSR path.
    (void)hipMemsetAsync(counts, 0, (size_t)n_nodes * sizeof(int), stream);
    const int eblocks = (n_edges + 255) / 256;
    hist_kernel<<<eblocks, 256, 0, stream>>>(dst, counts, n_edges);
    scan_kernel<<<1, 1024, 0, stream>>>(counts, offsets, n_nodes);
    fill1_kernel<<<eblocks, 256, 0, stream>>>(src, dst, offsets, esorted,
                                              n_edges);
    gather_update_kernel<<<512, 256, 0, stream>>>(h, W, b, counts, offsets,
                                                  esorted, out, n_nodes);
  }
}

// Round 8
// 177.787 us; speedup vs baseline: 7.3890x; 1.0351x over previous
//
#include <hip/hip_runtime.h>
#include <hip/hip_bf16.h>

static constexpr int HIDDEN = 128;

using bf16x8 = __attribute__((ext_vector_type(8))) __bf16;
using f32x4 = __attribute__((ext_vector_type(4))) float;
using ushort8v = __attribute__((ext_vector_type(8))) ushort;

__device__ inline ushort f2bf(float x) {
  __hip_bfloat16 t = __float2bfloat16(x);
  return *reinterpret_cast<ushort*>(&t);
}

// ---------------------------------------------------------------------------
// hist (4 edges/thread) fused with wconv (W fp32 -> bf16) on trailing blocks.
// ---------------------------------------------------------------------------
__global__ void __launch_bounds__(256) hist_wconv_kernel(
    const int* __restrict__ dst, int* __restrict__ counts, int n_edges,
    int nbh, const float* __restrict__ W, ushort* __restrict__ wbf) {
  if (blockIdx.x < nbh) {
    int i = (blockIdx.x * 256 + threadIdx.x) * 4;
    if (i + 3 < n_edges) {
      int4 d = *reinterpret_cast<const int4*>(dst + i);
      atomicAdd(&counts[d.x], 1);
      atomicAdd(&counts[d.y], 1);
      atomicAdd(&counts[d.z], 1);
      atomicAdd(&counts[d.w], 1);
    } else {
      for (int j = i; j < n_edges; ++j) atomicAdd(&counts[dst[j]], 1);
    }
  } else {
    int i = ((blockIdx.x - nbh) * 256 + threadIdx.x) * 4;
    if (i < HIDDEN * HIDDEN) {
      float4 w = *reinterpret_cast<const float4*>(W + i);
      ushort4 u;
      u.x = f2bf(w.x);
      u.y = f2bf(w.y);
      u.z = f2bf(w.z);
      u.w = f2bf(w.w);
      *reinterpret_cast<ushort4*>(wbf + i) = u;
    }
  }
}

// Phase A: per-tile (1024 elements) sums.
__global__ void __launch_bounds__(256) scanA_kernel(
    const int* __restrict__ counts, int* __restrict__ tilesums, int n) {
  const int t = threadIdx.x;
  const int base = blockIdx.x * 1024 + t * 4;
  int s = 0;
  if (base + 3 < n) {
    int4 v = *reinterpret_cast<const int4*>(counts + base);
    s = v.x + v.y + v.z + v.w;
  } else {
    for (int j = 0; j < 4; ++j)
      if (base + j < n) s += counts[base + j];
  }
  for (int off = 1; off < 64; off <<= 1) s += __shfl_xor(s, off, 64);
  __shared__ int wp[4];
  if ((t & 63) == 0) wp[t >> 6] = s;
  __syncthreads();
  if (t == 0) tilesums[blockIdx.x] = wp[0] + wp[1] + wp[2] + wp[3];
}

// Phase C (fused with B): every block wave-scans the <=64 tile sums, then
// writes exclusive offsets for its tile.
__global__ void __launch_bounds__(256) scanC_kernel(
    const int* __restrict__ counts, const int* __restrict__ tilesums,
    int* __restrict__ offsets, int n, int nt) {
  __shared__ int tp[64];
  const int t = threadIdx.x;
  if (t < 64) {
    int v = (t < nt) ? tilesums[t] : 0;
    int orig = v;
    for (int off = 1; off < 64; off <<= 1) {
      int u = __shfl_up(v, off, 64);
      if (t >= off) v += u;
    }
    tp[t] = v - orig;  // exclusive prefix of tiles
  }
  __syncthreads();

  const int base = blockIdx.x * 1024 + t * 4;
  int4 v = {0, 0, 0, 0};
  const bool full = (base + 3 < n);
  if (full) {
    v = *reinterpret_cast<const int4*>(counts + base);
  } else {
    if (base + 0 < n) v.x = counts[base + 0];
    if (base + 1 < n) v.y = counts[base + 1];
    if (base + 2 < n) v.z = counts[base + 2];
    if (base + 3 < n) v.w = counts[base + 3];
  }
  const int s = v.x + v.y + v.z + v.w;
  int inc = s;
  for (int off = 1; off < 64; off <<= 1) {
    int u = __shfl_up(inc, off, 64);
    if ((t & 63) >= off) inc += u;
  }
  const int excl = inc - s;
  __shared__ int wp[4];
  if ((t & 63) == 63) wp[t >> 6] = inc;
  __syncthreads();
  int wbase = 0;
  for (int w = 0; w < (t >> 6); ++w) wbase += wp[w];
  int p = tp[blockIdx.x] + wbase + excl;
  if (full) {
    int4 o;
    o.x = p;
    o.y = p + v.x;
    o.z = p + v.x + v.y;
    o.w = p + v.x + v.y + v.z;
    *reinterpret_cast<int4*>(offsets + base) = o;
  } else {
    int run = p;
    if (base + 0 < n) { offsets[base + 0] = run; run += v.x; }
    if (base + 1 < n) { offsets[base + 1] = run; run += v.y; }
    if (base + 2 < n) { offsets[base + 2] = run; run += v.z; }
    if (base + 3 < n) { offsets[base + 3] = run; }
  }
}

// ---------------------------------------------------------------------------
// Split-grid fusion: blocks [0, nbf) do CSR fill (4 edges/thread, atomic
// cursor); blocks [nbf, nbf+ntb) do hW = bf16(h) @ bf16(W).T via MFMA.
// The two phases have no data dependency and use disjoint resources
// (atomics/latency vs MFMA/BW) -> concurrent occupancy of the machine.
// ---------------------------------------------------------------------------
__global__ void __launch_bounds__(256) fill_transform_kernel(
    const int* __restrict__ src, const int* __restrict__ dst,
    int* __restrict__ offsets, int* __restrict__ esorted, int n_edges,
    int nbf, const float* __restrict__ h, const ushort* __restrict__ wbf,
    ushort* __restrict__ hW, int n_nodes) {
  constexpr int COLP = 136;  // pad: 272B row stride, 16B aligned
  __shared__ ushort tile[4][16][COLP];

  if (blockIdx.x < nbf) {
    // ---- fill ----
    int i = (blockIdx.x * 256 + threadIdx.x) * 4;
    if (i + 3 < n_edges) {
      int4 s = *reinterpret_cast<const int4*>(src + i);
      int4 d = *reinterpret_cast<const int4*>(dst + i);
      int p0 = atomicAdd(&offsets[d.x], 1);
      int p1 = atomicAdd(&offsets[d.y], 1);
      int p2 = atomicAdd(&offsets[d.z], 1);
      int p3 = atomicAdd(&offsets[d.w], 1);
      esorted[p0] = s.x;
      esorted[p1] = s.y;
      esorted[p2] = s.z;
      esorted[p3] = s.w;
    } else {
      for (int j = i; j < n_edges; ++j) {
        int pos = atomicAdd(&offsets[dst[j]], 1);
        esorted[pos] = src[j];
      }
    }
    return;
  }

  // ---- transform: wave handles 16 node-rows x 128 cols ----
  const int tb = blockIdx.x - nbf;
  const int wave = threadIdx.x >> 6;
  const int lane = threadIdx.x & 63;
  const int r16 = lane & 15;
  const int kq = lane >> 4;  // 0..3
  const int kbase = kq * 8;
  const int base = tb * 64 + wave * 16;

  int arow = base + r16;
  if (arow >= n_nodes) arow = n_nodes - 1;  // clamp (loads only)
  const float* hrow = h + (size_t)arow * HIDDEN;

  bf16x8 a[4];
#pragma unroll
  for (int ks = 0; ks < 4; ++ks) {
    const float4 u = *reinterpret_cast<const float4*>(hrow + ks * 32 + kbase);
    const float4 v =
        *reinterpret_cast<const float4*>(hrow + ks * 32 + kbase + 4);
    bf16x8 t;
    t[0] = (__bf16)u.x;
    t[1] = (__bf16)u.y;
    t[2] = (__bf16)u.z;
    t[3] = (__bf16)u.w;
    t[4] = (__bf16)v.x;
    t[5] = (__bf16)v.y;
    t[6] = (__bf16)v.z;
    t[7] = (__bf16)v.w;
    a[ks] = t;
  }

#pragma unroll
  for (int ct = 0; ct < 8; ++ct) {
    const ushort* wrow = wbf + (size_t)(ct * 16 + r16) * HIDDEN;
    f32x4 acc = {0.f, 0.f, 0.f, 0.f};
#pragma unroll
    for (int ks = 0; ks < 4; ++ks) {
      bf16x8 bfrag = *reinterpret_cast<const bf16x8*>(wrow + ks * 32 + kbase);
      acc = __builtin_amdgcn_mfma_f32_16x16x32_bf16(a[ks], bfrag, acc, 0, 0, 0);
    }
#pragma unroll
    for (int r = 0; r < 4; ++r)
      tile[wave][kq * 4 + r][ct * 16 + r16] = f2bf(acc[r]);
  }
  // Wave-local LDS roundtrip: each wave touches only tile[wave]; compiler
  // orders ds_write->ds_read via lgkmcnt. No barrier needed.
#pragma unroll
  for (int it = 0; it < 4; ++it) {
    const int row = it * 4 + (lane >> 4);
    const int cb = r16 * 8;
    const int nrow = base + row;
    if (nrow < n_nodes) {
      ushort8v v = *reinterpret_cast<const ushort8v*>(&tile[wave][row][cb]);
      *reinterpret_cast<ushort8v*>(hW + (size_t)nrow * HIDDEN + cb) = v;
    }
  }
}

// ---------------------------------------------------------------------------
// out[i] = deg>0 ? sum(hW[src]) + b : h[i].
// 8 lanes/node, 32B (2x uint4) per lane: fewer broadcasts, 2x per-lane MLP.
// Nontemporal on esorted (read-once) and out (write-once); hW stays cached.
// ---------------------------------------------------------------------------
__global__ void __launch_bounds__(256) gather_sum_kernel(
    const ushort* __restrict__ hW, const float* __restrict__ h,
    const float* __restrict__ b, const int* __restrict__ counts,
    const int* __restrict__ ends, const int* __restrict__ esorted,
    float* __restrict__ out, int n_nodes) {
  const int lane = threadIdx.x & 7;    // 8 lanes/node
  const int group = threadIdx.x >> 3;  // 32 nodes/block
  const int f0 = lane * 16;            // 16 floats per lane
  const int node = blockIdx.x * 32 + group;
  if (node >= n_nodes) return;

  const int deg = counts[node];
  f32x4 A = {0.f, 0.f, 0.f, 0.f};
  f32x4 B = {0.f, 0.f, 0.f, 0.f};
  f32x4 C = {0.f, 0.f, 0.f, 0.f};
  f32x4 D = {0.f, 0.f, 0.f, 0.f};
  if (deg == 0) {
    const float* hr = h + (size_t)node * HIDDEN + f0;
    float4 t0 = *reinterpret_cast<const float4*>(hr + 0);
    float4 t1 = *reinterpret_cast<const float4*>(hr + 4);
    float4 t2 = *reinterpret_cast<const float4*>(hr + 8);
    float4 t3 = *reinterpret_cast<const float4*>(hr + 12);
    A = {t0.x, t0.y, t0.z, t0.w};
    B = {t1.x, t1.y, t1.z, t1.w};
    C = {t2.x, t2.y, t2.z, t2.w};
    D = {t3.x, t3.y, t3.z, t3.w};
  } else {
    const int start = ends[node] - deg;
    for (int base = 0; base < deg; base += 8) {
      int sreg = 0;
      if (base + lane < deg)
        sreg = __builtin_nontemporal_load(esorted + start + base + lane);
      const int m = min(8, deg - base);
#pragma unroll 8
      for (int jj = 0; jj < m; ++jj) {
        int s = __shfl(sreg, jj, 8);
        const uint4* rp =
            reinterpret_cast<const uint4*>(hW + (size_t)s * HIDDEN + f0);
        uint4 v0 = rp[0];
        uint4 v1 = rp[1];
        A[0] += __uint_as_float(v0.x << 16);
        A[1] += __uint_as_float(v0.x & 0xffff0000u);
        A[2] += __uint_as_float(v0.y << 16);
        A[3] += __uint_as_float(v0.y & 0xffff0000u);
        B[0] += __uint_as_float(v0.z << 16);
        B[1] += __uint_as_float(v0.z & 0xffff0000u);
        B[2] += __uint_as_float(v0.w << 16);
        B[3] += __uint_as_float(v0.w & 0xffff0000u);
        C[0] += __uint_as_float(v1.x << 16);
        C[1] += __uint_as_float(v1.x & 0xffff0000u);
        C[2] += __uint_as_float(v1.y << 16);
        C[3] += __uint_as_float(v1.y & 0xffff0000u);
        D[0] += __uint_as_float(v1.z << 16);
        D[1] += __uint_as_float(v1.z & 0xffff0000u);
        D[2] += __uint_as_float(v1.w << 16);
        D[3] += __uint_as_float(v1.w & 0xffff0000u);
      }
    }
    const float4 b0 = *reinterpret_cast<const float4*>(b + f0 + 0);
    const float4 b1 = *reinterpret_cast<const float4*>(b + f0 + 4);
    const float4 b2 = *reinterpret_cast<const float4*>(b + f0 + 8);
    const float4 b3 = *reinterpret_cast<const float4*>(b + f0 + 12);
    A[0] += b0.x; A[1] += b0.y; A[2] += b0.z; A[3] += b0.w;
    B[0] += b1.x; B[1] += b1.y; B[2] += b1.z; B[3] += b1.w;
    C[0] += b2.x; C[1] += b2.y; C[2] += b2.z; C[3] += b2.w;
    D[0] += b3.x; D[1] += b3.y; D[2] += b3.z; D[3] += b3.w;
  }
  float* op = out + (size_t)node * HIDDEN + f0;
  __builtin_nontemporal_store(A, reinterpret_cast<f32x4*>(op + 0));
  __builtin_nontemporal_store(B, reinterpret_cast<f32x4*>(op + 4));
  __builtin_nontemporal_store(C, reinterpret_cast<f32x4*>(op + 8));
  __builtin_nontemporal_store(D, reinterpret_cast<f32x4*>(op + 12));
}

// ---------------------------------------------------------------------------
// Fallback (ws too small): R1 fused CSR path.
// ---------------------------------------------------------------------------

__global__ void __launch_bounds__(256) hist_kernel(
    const int* __restrict__ dst, int* __restrict__ counts, int n_edges) {
  int i = blockIdx.x * 256 + threadIdx.x;
  if (i < n_edges) atomicAdd(&counts[dst[i]], 1);
}

__global__ void __launch_bounds__(256) fill1_kernel(
    const int* __restrict__ src, const int* __restrict__ dst,
    int* __restrict__ offsets, int* __restrict__ esorted, int n_edges) {
  int i = blockIdx.x * 256 + threadIdx.x;
  if (i < n_edges) {
    int pos = atomicAdd(&offsets[dst[i]], 1);
    esorted[pos] = src[i];
  }
}

__global__ void __launch_bounds__(1024) scan_kernel(
    const int* __restrict__ counts, int* __restrict__ offsets, int n) {
  __shared__ int part[1024];
  const int t = threadIdx.x;
  const int C = (n + 1023) / 1024;
  const int base = t * C;
  int sum = 0;
  for (int j = 0; j < C; ++j) {
    int idx = base + j;
    if (idx < n) sum += counts[idx];
  }
  part[t] = sum;
  __syncthreads();
  for (int s = 1; s < 1024; s <<= 1) {
    int v = (t >= s) ? part[t - s] : 0;
    __syncthreads();
    part[t] += v;
    __syncthreads();
  }
  int run = part[t] - sum;
  for (int j = 0; j < C; ++j) {
    int idx = base + j;
    if (idx < n) {
      offsets[idx] = run;
      run += counts[idx];
    }
  }
}

__global__ void __launch_bounds__(256, 2) gather_update_kernel(
    const float* __restrict__ h, const float* __restrict__ W,
    const float* __restrict__ b, const int* __restrict__ counts,
    const int* __restrict__ ends, const int* __restrict__ esorted,
    float* __restrict__ out, int n_nodes) {
  __shared__ float Wt[HIDDEN][HIDDEN];
  for (int i = threadIdx.x; i < HIDDEN * HIDDEN / 4; i += 256) {
    int idx = i * 4;
    int j = idx >> 7;
    int k = idx & 127;
    float4 w = *reinterpret_cast<const float4*>(W + j * HIDDEN + k);
    Wt[k + 0][j] = w.x;
    Wt[k + 1][j] = w.y;
    Wt[k + 2][j] = w.z;
    Wt[k + 3][j] = w.w;
  }
  __syncthreads();
  const int lane = threadIdx.x & 31;
  const int group = threadIdx.x >> 5;
  const int j0 = lane * 4;
  const float4 bias = *reinterpret_cast<const float4*>(b + j0);
  const int nb = (n_nodes + 7) >> 3;
  for (int batch = blockIdx.x; batch < nb; batch += gridDim.x) {
    int node = batch * 8 + group;
    if (node >= n_nodes) continue;
    const int deg = counts[node];
    float4 res;
    if (deg == 0) {
      res = reinterpret_cast<const float4*>(h + (size_t)node * HIDDEN)[lane];
    } else {
      const int start = ends[node] - deg;
      float4 acc = {0.f, 0.f, 0.f, 0.f};
      for (int basei = 0; basei < deg; basei += 32) {
        int sreg = 0;
        if (basei + lane < deg) sreg = esorted[start + basei + lane];
        const int m = min(32, deg - basei);
        for (int jj = 0; jj < m; ++jj) {
          int s = __shfl(sreg, jj, 32);
          float4 v =
              reinterpret_cast<const float4*>(h + (size_t)s * HIDDEN)[lane];
          acc.x += v.x;
          acc.y += v.y;
          acc.z += v.z;
          acc.w += v.w;
        }
      }
      const float* av = reinterpret_cast<const float*>(&acc);
      float4 o = bias;
#pragma unroll
      for (int k = 0; k < HIDDEN; ++k) {
        float aval = __shfl(av[k & 3], k >> 2, 32);
        float4 w = *reinterpret_cast<const float4*>(&Wt[k][j0]);
        o.x = fmaf(aval, w.x, o.x);
        o.y = fmaf(aval, w.y, o.y);
        o.z = fmaf(aval, w.z, o.z);
        o.w = fmaf(aval, w.w, o.w);
      }
      res = o;
    }
    reinterpret_cast<float4*>(out + (size_t)node * HIDDEN)[lane] = res;
  }
}

// ---------------------------------------------------------------------------

extern "C" void kernel_launch(void* const* d_in, const int* in_sizes, int n_in,
                              void* d_out, int out_size, void* d_ws, size_t ws_size,
                              hipStream_t stream) {
  const float* h = (const float*)d_in[0];
  const float* W = (const float*)d_in[1];
  const float* b = (const float*)d_in[2];
  const int* src = (const int*)d_in[3];
  const int* dst = (const int*)d_in[4];
  float* out = (float*)d_out;
  const int n_nodes = in_sizes[0] / HIDDEN;
  const int n_edges = in_sizes[3];

  const int n_round = (n_nodes + 1023) & ~1023;  // multiple of 1024
  const int nt = n_round / 1024;                 // tiles for scan
  const int eblocks4 = (n_edges + 1023) / 1024;  // 4 edges/thread

  // ws layout (ints): counts | offsets | tilesums(64) | esorted | hW | wbf
  int* counts = (int*)d_ws;
  int* offsets = counts + n_round;
  int* tilesums = offsets + n_round;
  int* esorted = tilesums + 64;
  size_t off_bytes = ((size_t)(2 * n_round + 64 + n_edges) * 4 + 15) & ~15ull;
  ushort* hW = (ushort*)((char*)d_ws + off_bytes);
  size_t wbf_off = (off_bytes + (size_t)n_nodes * HIDDEN * 2 + 15) & ~15ull;
  ushort* wbf = (ushort*)((char*)d_ws + wbf_off);
  const size_t need_full = wbf_off + (size_t)HIDDEN * HIDDEN * 2;

  if (ws_size >= need_full && nt <= 64) {
    (void)hipMemsetAsync(counts, 0, (size_t)n_nodes * sizeof(int), stream);
    const int wblocks = (HIDDEN * HIDDEN + 1023) / 1024;
    hist_wconv_kernel<<<eblocks4 + wblocks, 256, 0, stream>>>(
        dst, counts, n_edges, eblocks4, W, wbf);
    scanA_kernel<<<nt, 256, 0, stream>>>(counts, tilesums, n_nodes);
    scanC_kernel<<<nt, 256, 0, stream>>>(counts, tilesums, offsets, n_nodes,
                                         nt);
    const int tblocks = (n_nodes + 63) / 64;
    fill_transform_kernel<<<eblocks4 + tblocks, 256, 0, stream>>>(
        src, dst, offsets, esorted, n_edges, eblocks4, h, wbf, hW, n_nodes);
    const int gblocks = (n_nodes + 31) / 32;
    gather_sum_kernel<<<gblocks, 256, 0, stream>>>(hW, h, b, counts, offsets,
                                                   esorted, out, n_nodes);
  } else {
    // Fallback: R1 fused CSR path.
    (void)hipMemsetAsync(counts, 0, (size_t)n_nodes * sizeof(int), stream);
    const int eblocks = (n_edges + 255) / 256;
    hist_kernel<<<eblocks, 256, 0, stream>>>(dst, counts, n_edges);
    scan_kernel<<<1, 1024, 0, stream>>>(counts, offsets, n_nodes);
    fill1_kernel<<<eblocks, 256, 0, stream>>>(src, dst, offsets, esorted,
                                              n_edges);
    gather_update_kernel<<<512, 256, 0, stream>>>(h, W, b, counts, offsets,
                                                  esorted, out, n_nodes);
  }
}